// Round 5
// baseline (194.663 us; speedup 1.0000x reference)
//
#include <hip/hip_runtime.h>
#include <math.h>

// ConvBertLightConv: dynamic depthwise conv with softmax-normalized per-(pos,head) kernels.
// B=8, S=4096, D=768 (12 heads x 64), K=9, 'same' zero padding along S.
// out[b,s,h,d] = sum_k softmax(filters[b,s,h,:])[k] * x[b, s+k-4, h*64+d]
//
// R7: R6's multi-tile counted-vmcnt pipeline, de-risked. R6 NaN'd: the
// unproven 12-byte filter global_load_lds left LDS garbage -> exp(garbage)
// = inf -> inf*0 = NaN. Fixes:
//  - Filters NEVER touch LDS/gll. Per tile, a wave's 64 lanes own the 64
//    (s,head) pairs (16 s x 4 heads): 9 plain VGPR loads + ONE softmax per
//    lane, weights read in compute via __shfl from owner lane sl*4+h.
//    Zero ds_writes in the whole kernel.
//  - Counted waits are compiler-derived, not hand-counted: issue order
//    fload(j+1) -> gll_x(j+1)x6 -> softmax(j+1). The compiler's auto-wait
//    for the fload values is vmcnt(6); vmcnt completes IN ORDER, so <=6
//    outstanding (the 6 newest = gll(j+1)) proves gll(j) landed. Defensive
//    explicit vmcnt(6) before the barrier; NEVER vmcnt(0) mid-loop.
//  - sched_barrier(0) pins every phase boundary (raw s_barrier + asm waits
//    alone don't stop the machine scheduler from hoisting/sinking).
// Pipeline: block owns 8 consecutive 16-row tiles, xs double-buffered
// (48 KB -> 3 blocks/CU, grid 768 co-resident). Steady in-flight ~6 KB/wave
// x 12 waves/CU ~ 72 KB/CU >> ~5 KB Little's-law need for 6.3 TB/s.

#define KS 9
#define HD 64
#define NH 12
#define DMODEL 768              // NH*HD
#define SEQ 4096
#define BATCH 8
#define TTILE 16                // s-positions per tile
#define NROWS (TTILE + KS - 1)  // 24 x-rows incl. halo
#define HG 4                    // heads per block
#define NHG (NH / HG)           // 3
#define DBLK (HG * HD)          // 256 floats (1 KB) per row-slice
#define FSTRIDE (NH * KS)       // 108 filter floats per position
#define FW (HG * KS)            // 36 filter floats per (s, head-group)
#define NT 8                    // tiles per block
#define BLK_S (NT * TTILE)      // 128 s-positions per block
#define NTHREADS 256            // 4 waves

#define SB0() __builtin_amdgcn_sched_barrier(0)

__global__ __launch_bounds__(NTHREADS, 3) void lightconv_kernel(
    const float* __restrict__ x,      // [B, S, 768]
    const float* __restrict__ filt,   // [B, S, 108]
    float* __restrict__ out)          // [B, S, 768]
{
    __shared__ float xs[2][NROWS * DBLK];  // 2 * 24 KB = 48 KB

    const int cr    = blockIdx.x & 31;     // chunk-range 0..31 (SEQ/BLK_S = 32)
    const int pairi = blockIdx.x >> 5;     // 0..23
    const int hg    = pairi % NHG;
    const int b     = pairi / NHG;
    const int sbase = cr * BLK_S;
    const int t     = threadIdx.x;
    const int wave  = t >> 6;              // 0..3
    const int lane  = t & 63;

    const float* xbase = x + (size_t)b * SEQ * DMODEL + hg * DBLK + lane * 4;
    // filter ownership: lane l owns pair (sl = l>>2, h = l&3) of every tile;
    // its 9 taps are CONSECUTIVE floats (compiler may widen the loads; the
    // derived waits stay correct since the 6 glls are always newest).
    const float* fown = filt + (size_t)b * SEQ * FSTRIDE + hg * FW
                        + (size_t)(lane >> 2) * FSTRIDE + (lane & 3) * KS;

    float wcur[KS], wnext[KS];

    auto fload = [&](int ts0) {
#pragma unroll
        for (int k = 0; k < KS; ++k) wnext[k] = fown[(size_t)ts0 * FSTRIDE + k];
    };
    auto softmax_next = [&]() {
        float mx = -1e30f;
#pragma unroll
        for (int k = 0; k < KS; ++k) mx = fmaxf(mx, wnext[k]);
        float sum = 0.f;
#pragma unroll
        for (int k = 0; k < KS; ++k) { wnext[k] = __expf(wnext[k] - mx); sum += wnext[k]; }
        const float inv = 1.0f / sum;
#pragma unroll
        for (int k = 0; k < KS; ++k) wnext[k] *= inv;
    };
    auto stage_x = [&](int ts0, int p) {     // 6 x 16B gll per wave (proven path)
#pragma unroll
        for (int jj = 0; jj < NROWS / 4; ++jj) {
            const int r = wave * (NROWS / 4) + jj;
            int ss = ts0 + r - (KS / 2);
            ss = ss < 0 ? 0 : (ss > SEQ - 1 ? SEQ - 1 : ss);  // clamp; weight-zeroed below
            __builtin_amdgcn_global_load_lds(
                (const __attribute__((address_space(1))) void*)(xbase + (size_t)ss * DMODEL),
                (__attribute__((address_space(3))) void*)&xs[p][r * DBLK],
                16, 0, 0);
        }
    };

    // ---- prologue: tile 0 filters + x, softmax under the gll shadow ----
    fload(sbase);
    SB0();
    stage_x(sbase, 0);
    SB0();
    softmax_next();                 // compiler auto-wait ~vmcnt(6): gll(0) stays in flight
    SB0();

#pragma unroll
    for (int j = 0; j < NT; ++j) {
#pragma unroll
        for (int k = 0; k < KS; ++k) wcur[k] = wnext[k];

        if (j + 1 < NT) {
            fload(sbase + (j + 1) * TTILE);
            SB0();
            stage_x(sbase + (j + 1) * TTILE, (j + 1) & 1);
            SB0();
            softmax_next();         // drains up to gll(j+1): gll(j), stores(j-1) done
            SB0();
            asm volatile("s_waitcnt vmcnt(6)" ::: "memory");  // defensive; not 0
        } else {
            asm volatile("s_waitcnt vmcnt(0)" ::: "memory");  // last tile: full drain ok
        }
        SB0();
        __builtin_amdgcn_s_barrier();   // xs[j&1] staged by all waves
        SB0();

        // ---- compute tile j from xs[j&1]; weights via in-wave shuffles ----
        {
            const int ts0 = sbase + j * TTILE;
            const bool guard = (j == 0 && sbase == 0) ||
                               (j == NT - 1 && sbase == SEQ - BLK_S);
            const int h = lane >> 4;            // head-in-group 0..3
#pragma unroll
            for (int i = 0; i < 4; ++i) {
                const int sl  = wave * 4 + i;   // output row in tile
                const int src = (sl << 2) | h;  // owner lane of (sl, h)
                float4 acc = make_float4(0.f, 0.f, 0.f, 0.f);
#pragma unroll
                for (int k = 0; k < KS; ++k) {
                    float wk = __shfl(wcur[k], src);
                    if (guard) {
                        const int ssg = ts0 + sl + k - (KS / 2);
                        if (ssg < 0 || ssg >= SEQ) wk = 0.f;   // zero-pad semantics
                    }
                    const float4 xv = *reinterpret_cast<const float4*>(
                        &xs[j & 1][(sl + k) * DBLK + lane * 4]);
                    acc.x += wk * xv.x;
                    acc.y += wk * xv.y;
                    acc.z += wk * xv.z;
                    acc.w += wk * xv.w;
                }
                *reinterpret_cast<float4*>(
                    out + ((size_t)b * SEQ + ts0 + sl) * DMODEL + hg * DBLK + lane * 4) = acc;
            }
        }
        SB0();
        __builtin_amdgcn_s_barrier();   // xs[j&1] reads done before gll(j+2) overwrites
        SB0();
    }
}

extern "C" void kernel_launch(void* const* d_in, const int* in_sizes, int n_in,
                              void* d_out, int out_size, void* d_ws, size_t ws_size,
                              hipStream_t stream) {
    const float* x    = (const float*)d_in[0];   // [8,4096,768] fp32
    const float* filt = (const float*)d_in[1];   // [8,4096,108] fp32
    float* out        = (float*)d_out;           // [8,4096,12,64] fp32

    const int grid = BATCH * NHG * (SEQ / BLK_S);  // 8*3*32 = 768 = 3 blocks/CU
    lightconv_kernel<<<grid, NTHREADS, 0, stream>>>(x, filt, out);
}